// Round 13
// baseline (433.735 us; speedup 1.0000x reference)
//
#include <hip/hip_runtime.h>
#include <hip/hip_bf16.h>
#include <math.h>

#define BB 8
#define NN 200000
#define CC 81
#define TOPK 200
#define CAP 8192
#define NBIN 4096
#define THKEY 0x3E800000u   // bits of 0.25f: static prefilter threshold

static __device__ __forceinline__ int bin_of(unsigned key) {
    return (int)((key >> 14) & (NBIN - 1));
}

// ---------------------------------------------------------------------------
// Kernel Z: zero the 8 per-batch candidate counters.
// ---------------------------------------------------------------------------
__global__ __launch_bounds__(64) void zero_kernel(int* __restrict__ cnt) {
    if (threadIdx.x < BB) cnt[threadIdx.x] = 0;
}

// ---------------------------------------------------------------------------
// Kernel A (v5): proven v4 scores pipeline (async global_load_lds staging +
// fused max/sum; 89.6us @ ~92% achievable HBM, R11) + candidate APPEND:
// rows with key >= bits(0.25) are pushed (key,idx) to the per-batch list.
// Expected ~1300/batch appends (top-200 score analytically ~0.34).
// grid = (NN/64, BB) = (3125, 8), block = 256.
// ---------------------------------------------------------------------------
__global__ __launch_bounds__(256) void scores_kernel(const float* __restrict__ logits,
                                                     float* __restrict__ scores,
                                                     unsigned long long* __restrict__ cand,
                                                     int* __restrict__ cnt) {
    __shared__ float ls[64 * CC];     // 5184 floats = 20.7 KB
    __shared__ float lsc[64];
    int tid = threadIdx.x;
    int b = blockIdx.y;
    size_t fbase = ((size_t)b * NN + (size_t)blockIdx.x * 64) * CC;  // 16B-aligned
    const float4* g4 = (const float4*)(logits + fbase);
    float4* l4 = (float4*)ls;

    int wbase = tid & ~63;            // wave-uniform base within block
#pragma unroll
    for (int k = 0; k < 5; ++k) {     // 5 full wave rounds = 1280 float4s
        __builtin_amdgcn_global_load_lds(
            (const __attribute__((address_space(1))) void*)(g4 + k * 256 + tid),
            (__attribute__((address_space(3))) void*)(l4 + k * 256 + wbase),
            16, 0, 0);
    }
    if (tid < 16) l4[1280 + tid] = g4[1280 + tid];   // tail 16 f4s, plain copy
    __syncthreads();                  // drains vmcnt incl. global_load_lds

    int r = tid >> 2;                 // row 0..63
    int q = tid & 3;                  // quarter
    const float* row = ls + r * CC;
    int head = (4 - (r & 3)) & 3;     // floats until 16B alignment (81r%4==r%4)
    int nf4 = (CC - head) >> 2;       // 19 or 20 aligned float4s
    int tail = CC - head - 4 * nf4;   // 0..3

    float m = -INFINITY, S = 0.0f;
    const float4* rp = (const float4*)(row + head);
    for (int j = q; j < nf4; j += 4) {
        float4 v = rp[j];
        m = fmaxf(fmaxf(fmaxf(m, v.x), v.y), fmaxf(v.z, v.w));
        S += __expf(v.x) + __expf(v.y) + __expf(v.z) + __expf(v.w);
    }
    if (q == 3) {
        for (int h2 = 0; h2 < head; ++h2) { float x = row[h2]; m = fmaxf(m, x); S += __expf(x); }
        for (int t2 = 0; t2 < tail; ++t2) { float x = row[CC - tail + t2]; m = fmaxf(m, x); S += __expf(x); }
    }
#pragma unroll
    for (int w = 1; w < 4; w <<= 1) {
        m = fmaxf(m, __shfl_xor(m, w, 64));
        S += __shfl_xor(S, w, 64);
    }
    if (q == 0) {
        float s = __expf(m) / S;
        lsc[r] = s;
        unsigned key = __float_as_uint(s);
        if (key >= THKEY) {
            int pos = atomicAdd(&cnt[b], 1);
            if (pos < CAP)
                cand[(size_t)b * CAP + pos] =
                    ((unsigned long long)key << 32) | (unsigned)(blockIdx.x * 64 + r);
        }
    }
    __syncthreads();
    if (tid < 64) scores[(size_t)b * NN + (size_t)blockIdx.x * 64 + tid] = lsc[tid];
}

// ---------------------------------------------------------------------------
// Kernel B (tail, one block per batch, 1024 threads):
// FAST path (cnt in [200, CAP]): load compact candidate list (superset of
//   top-200 since >=200 scores clear the static threshold) -> proven
//   rank/re-rank/mask-scan NMS. No full-array scans.
// SLOW path (threshold mis-set / pathological data): full in-block
//   hist+threshold+gather (R5's proven code) -> same rank/NMS. Correct always.
// ---------------------------------------------------------------------------
__global__ __launch_bounds__(1024) void tail_kernel(const float* __restrict__ scores,
                                                    const float* __restrict__ segs,
                                                    const unsigned long long* __restrict__ cand,
                                                    const int* __restrict__ cnt,
                                                    int* __restrict__ out) {
    __shared__ unsigned k_key[CAP];           // 32 KB
    __shared__ int k_idx[CAP];                // 32 KB
    __shared__ unsigned h[NBIN];              // 16 KB (slow path only)
    __shared__ unsigned csum[256];
    __shared__ int s_t, s_cnt;
    __shared__ unsigned sel_k[TOPK];
    __shared__ int sel_i[TOPK];
    __shared__ int nms_i[TOPK];
    __shared__ float nms_x1[TOPK + 56], nms_x2[TOPK + 56];

    int b = blockIdx.x;
    int tid = threadIdx.x;
    const float* sc = scores + (size_t)b * NN;
    const float* sg = segs + (size_t)b * NN * 2;

    for (int i = tid; i < TOPK; i += 1024) {
        out[b * TOPK + i] = 0;
        out[(BB + b) * TOPK + i] = 0;
    }
    for (int i = tid; i < 56; i += 1024) { nms_x1[TOPK + i] = 0.f; nms_x2[TOPK + i] = 0.f; }

    int c = cnt[b];
    int M;
    if (c >= TOPK && c <= CAP) {
        // ---- FAST: compact candidate list ----
        M = c;
        for (int j = tid; j < M; j += 1024) {
            unsigned long long p = cand[(size_t)b * CAP + j];
            k_key[j] = (unsigned)(p >> 32);
            k_idx[j] = (int)(p & 0xffffffffull);
        }
        __syncthreads();
    } else {
        // ---- SLOW: full hist + threshold + gather (proven R5 code) ----
        for (int i = tid; i < NBIN; i += 1024) h[i] = 0u;
        if (tid == 0) s_cnt = 0;
        __syncthreads();
        const float4* sc4 = (const float4*)sc;
        for (int i = tid; i < NN / 4; i += 1024) {
            float4 v = sc4[i];
            atomicAdd(&h[bin_of(__float_as_uint(v.x))], 1u);
            atomicAdd(&h[bin_of(__float_as_uint(v.y))], 1u);
            atomicAdd(&h[bin_of(__float_as_uint(v.z))], 1u);
            atomicAdd(&h[bin_of(__float_as_uint(v.w))], 1u);
        }
        __syncthreads();
        unsigned s = 0;
        int hi = 0;
        if (tid < 256) {
            hi = NBIN - 1 - 16 * tid;
#pragma unroll
            for (int j = 0; j < 16; ++j) s += h[hi - j];
            csum[tid] = s;
        }
        __syncthreads();
        if (tid == 0) {
            unsigned run = 0;
            for (int t = 0; t < 256; ++t) { unsigned tmp = csum[t]; csum[t] = run; run += tmp; }
        }
        __syncthreads();
        if (tid < 256) {
            unsigned before = csum[tid];
            if (before < TOPK && before + s >= TOPK) {
                unsigned cum = before;
                for (int j = 0; j < 16; ++j) {
                    cum += h[hi - j];
                    if (cum >= TOPK) { s_t = hi - j; break; }
                }
            }
        }
        __syncthreads();
        int t = s_t;
        for (int i = tid; i < NN / 4; i += 1024) {
            const float4* sc4b = (const float4*)sc;
            float4 v = sc4b[i];
            unsigned keys[4] = { __float_as_uint(v.x), __float_as_uint(v.y),
                                 __float_as_uint(v.z), __float_as_uint(v.w) };
#pragma unroll
            for (int j = 0; j < 4; ++j) {
                if (bin_of(keys[j]) >= t) {
                    int pos = atomicAdd(&s_cnt, 1);
                    if (pos < CAP) { k_key[pos] = keys[j]; k_idx[pos] = 4 * i + j; }
                }
            }
        }
        __syncthreads();
        M = s_cnt; if (M > CAP) M = CAP;
    }

    // ---- exact top-200 by (key desc, idx desc) == stable argsort tail ----
    for (int j = tid; j < M; j += 1024) {
        unsigned kj = k_key[j];
        int ij = k_idx[j];
        int rank = 0;
        for (int m = 0; m < M; ++m) {
            unsigned km = k_key[m];
            rank += (km > kj) || (km == kj && k_idx[m] > ij);
        }
        if (rank < TOPK) { sel_k[rank] = kj; sel_i[rank] = ij; }
    }
    __syncthreads();

    // ---- re-rank into NMS priority order (key desc, idx asc) ----
    if (tid < TOPK) {
        unsigned kj = sel_k[tid];
        int ij = sel_i[tid];
        int r2 = 0;
        for (int m = 0; m < TOPK; ++m) {
            unsigned km = sel_k[m];
            r2 += (km > kj) || (km == kj && sel_i[m] < ij);
        }
        nms_i[r2] = ij;
        nms_x1[r2] = sg[2 * (size_t)ij];
        nms_x2[r2] = sg[2 * (size_t)ij + 1];
    }
    __syncthreads();

    // ---- mask-scan greedy NMS on wave 0 ----
    if (tid >= 64) return;
    int lane = tid;
    float rx1[4], rx2[4];
#pragma unroll
    for (int k = 0; k < 4; ++k) {
        rx1[k] = nms_x1[k * 64 + lane];
        rx2[k] = nms_x2[k * 64 + lane];
    }
    unsigned long long m0 = ~0ull, m1 = ~0ull, m2 = ~0ull, m3 = 0xffull;

    int* keep = out + b * TOPK;
    for (int it = 0; it < TOPK; ++it) {
        int p;
        if (m0)      p = __ffsll(m0) - 1;
        else if (m1) p = 64 + __ffsll(m1) - 1;
        else if (m2) p = 128 + __ffsll(m2) - 1;
        else if (m3) p = 192 + __ffsll(m3) - 1;
        else break;

        float wx1 = nms_x1[p];
        float wx2 = nms_x2[p];
        if (lane == 0) keep[it] = nms_i[p];

        unsigned long long mw[4] = { m0, m1, m2, m3 };
        unsigned long long nm[4];
#pragma unroll
        for (int k = 0; k < 4; ++k) {
            bool alive = (mw[k] >> lane) & 1ull;
            bool kill = false;
            if (alive) {
                int pos = k * 64 + lane;
                if (pos == p) kill = true;
                else {
                    float inter = fminf(rx2[k], wx2) - fmaxf(rx1[k], wx1);
                    kill = inter > 0.f;
                }
            }
            nm[k] = __ballot(alive && !kill);
        }
        m0 = nm[0]; m1 = nm[1]; m2 = nm[2]; m3 = nm[3];
    }
}

extern "C" void kernel_launch(void* const* d_in, const int* in_sizes, int n_in,
                              void* d_out, int out_size, void* d_ws, size_t ws_size,
                              hipStream_t stream) {
    const float* logits = (const float*)d_in[0];   // (8, 200000, 81) f32
    const float* segs   = (const float*)d_in[1];   // (8, 200000, 2)  f32
    int* out = (int*)d_out;                        // (16, 200) int32

    char* ws = (char*)d_ws;
    float*              scores = (float*)ws;                        // 6,400,000 B
    unsigned long long* cand   = (unsigned long long*)(ws + 6400000); // 8*8192*8 = 524,288 B
    int*                cnt    = (int*)(ws + 6400000 + 524288);     // 32 B

    zero_kernel<<<1, 64, 0, stream>>>(cnt);
    dim3 sgrid(NN / 64, BB);                       // 3125 x 8
    scores_kernel<<<sgrid, 256, 0, stream>>>(logits, scores, cand, cnt);
    tail_kernel<<<BB, 1024, 0, stream>>>(scores, segs, cand, cnt, out);
}

// Round 14
// 203.824 us; speedup vs baseline: 2.1280x; 2.1280x over previous
//
#include <hip/hip_runtime.h>
#include <hip/hip_bf16.h>
#include <math.h>

#define BB 8
#define NN 200000
#define CC 81
#define TOPK 200
#define CAP 4096
#define NBIN 4096
#define NPART 16

static __device__ __forceinline__ int bin_of(unsigned key) {
    // score in [1/81, 1] -> exponent in [120,127]; bits above bit 25 constant.
    // 12-bit monotone bin: exp low-3 bits + top-9 mantissa bits.
    return (int)((key >> 14) & (NBIN - 1));
}

// ---------------------------------------------------------------------------
// Kernel A (v4, proven 89.6us @ ~92% achievable HBM): async global_load_lds
// staging + fused max/sum reduction. Block x==0 additionally zeroes the tail's
// per-batch sync words (runs strictly before the tail dispatch).
// grid = (NN/64, BB) = (3125, 8), block = 256.
// ---------------------------------------------------------------------------
__global__ __launch_bounds__(256) void scores_kernel(const float* __restrict__ logits,
                                                     float* __restrict__ scores,
                                                     int* __restrict__ sync) {
    __shared__ float ls[64 * CC];     // 5184 floats = 20.7 KB
    __shared__ float lsc[64];
    int tid = threadIdx.x;
    int b = blockIdx.y;
    if (blockIdx.x == 0 && tid == 0) {
        sync[b * 32] = 0;             // done1
        sync[256 + b * 32] = 0;       // done2
        sync[512 + b * 32] = 0;       // cnt
    }
    size_t fbase = ((size_t)b * NN + (size_t)blockIdx.x * 64) * CC;  // 16B-aligned
    const float4* g4 = (const float4*)(logits + fbase);
    float4* l4 = (float4*)ls;

    int wbase = tid & ~63;            // wave-uniform base within block
#pragma unroll
    for (int k = 0; k < 5; ++k) {     // 5 full wave rounds = 1280 float4s
        __builtin_amdgcn_global_load_lds(
            (const __attribute__((address_space(1))) void*)(g4 + k * 256 + tid),
            (__attribute__((address_space(3))) void*)(l4 + k * 256 + wbase),
            16, 0, 0);
    }
    if (tid < 16) l4[1280 + tid] = g4[1280 + tid];   // tail 16 f4s, plain copy
    __syncthreads();                  // drains vmcnt incl. global_load_lds

    int r = tid >> 2;                 // row 0..63
    int q = tid & 3;                  // quarter
    const float* row = ls + r * CC;
    int head = (4 - (r & 3)) & 3;     // floats until 16B alignment (81r%4==r%4)
    int nf4 = (CC - head) >> 2;       // 19 or 20 aligned float4s
    int tail = CC - head - 4 * nf4;   // 0..3

    float m = -INFINITY, S = 0.0f;
    const float4* rp = (const float4*)(row + head);
    for (int j = q; j < nf4; j += 4) {
        float4 v = rp[j];
        m = fmaxf(fmaxf(fmaxf(m, v.x), v.y), fmaxf(v.z, v.w));
        S += __expf(v.x) + __expf(v.y) + __expf(v.z) + __expf(v.w);
    }
    if (q == 3) {
        for (int h2 = 0; h2 < head; ++h2) { float x = row[h2]; m = fmaxf(m, x); S += __expf(x); }
        for (int t2 = 0; t2 < tail; ++t2) { float x = row[CC - tail + t2]; m = fmaxf(m, x); S += __expf(x); }
    }
#pragma unroll
    for (int w = 1; w < 4; w <<= 1) {
        m = fmaxf(m, __shfl_xor(m, w, 64));
        S += __shfl_xor(S, w, 64);
    }
    if (q == 0) lsc[r] = __expf(m) / S;
    __syncthreads();
    if (tid < 64) scores[(size_t)b * NN + (size_t)blockIdx.x * 64 + tid] = lsc[tid];
}

// ---------------------------------------------------------------------------
// Kernel T (fused tail, ONE dispatch): grid (NPART, BB) = 128 blocks, 256 thr.
// All blocks co-resident (38KB LDS -> 4 blocks/CU; 128 << 1024 slots), so
// in-kernel barriers are safe.
//   P1: per-block LDS partial hist -> parts slice; release done1[b].
//   P2: spin-acquire done1[b]==NPART; exact rank-200 threshold from parts
//       (proven R10 code); gather slice -> cand via cnt atomic; ACQ_REL
//       ticket on done2[b].
//   P3: last block (ticket NPART-1) per batch: proven rank / re-rank /
//       mask-scan NMS at 256 threads.
// ---------------------------------------------------------------------------
__global__ __launch_bounds__(256) void tail_fused(const float* __restrict__ scores,
                                                  const float* __restrict__ segs,
                                                  unsigned* __restrict__ parts,
                                                  int* __restrict__ cand,
                                                  int* __restrict__ sync,
                                                  int* __restrict__ out) {
    __shared__ unsigned h[NBIN];      // P1 hist; reused as k_key in P3
    __shared__ int k_idx[CAP];
    __shared__ unsigned csum[256];
    __shared__ int s_t, s_tick;
    __shared__ unsigned sel_k[TOPK];
    __shared__ int sel_i[TOPK];
    __shared__ int nms_i[TOPK];
    __shared__ float nms_x1[TOPK + 56], nms_x2[TOPK + 56];

    int tid = threadIdx.x;
    int bx = blockIdx.x;
    int b = blockIdx.y;
    int* done1 = sync + b * 32;
    int* done2 = sync + 256 + b * 32;
    int* cntb  = sync + 512 + b * 32;
    const float* sc = scores + (size_t)b * NN;
    const float* sg = segs + (size_t)b * NN * 2;

    // ---- P1: partial histogram ----
    for (int i = tid; i < NBIN; i += 256) h[i] = 0u;
    __syncthreads();
    const float4* sc4 = (const float4*)sc;
    for (int i = bx * 256 + tid; i < NN / 4; i += NPART * 256) {
        float4 v = sc4[i];
        atomicAdd(&h[bin_of(__float_as_uint(v.x))], 1u);
        atomicAdd(&h[bin_of(__float_as_uint(v.y))], 1u);
        atomicAdd(&h[bin_of(__float_as_uint(v.z))], 1u);
        atomicAdd(&h[bin_of(__float_as_uint(v.w))], 1u);
    }
    __syncthreads();
    unsigned* gp = parts + ((size_t)b * NPART + bx) * NBIN;
    for (int i = tid; i < NBIN; i += 256) gp[i] = h[i];
    __threadfence();                  // publish parts slice (agent scope)
    __syncthreads();
    if (tid == 0)
        __hip_atomic_fetch_add(done1, 1, __ATOMIC_RELEASE, __HIP_MEMORY_SCOPE_AGENT);

    // ---- barrier: all parts for batch b ready ----
    if (tid == 0) {
        while (__hip_atomic_load(done1, __ATOMIC_ACQUIRE, __HIP_MEMORY_SCOPE_AGENT) < NPART) {}
    }
    __syncthreads();
    __threadfence();                  // invalidate stale cached lines

    // ---- P2: threshold (proven R10 gather code) ----
    const unsigned* gpp = parts + (size_t)b * NPART * NBIN;
    int hi = NBIN - 1 - 16 * tid;
    unsigned binsum[16];
    unsigned s = 0;
#pragma unroll
    for (int j = 0; j < 16; ++j) {
        unsigned acc = 0;
#pragma unroll
        for (int p = 0; p < NPART; ++p) acc += gpp[p * NBIN + (hi - j)];
        binsum[j] = acc;
        s += acc;
    }
    csum[tid] = s;
    __syncthreads();
    if (tid == 0) {
        unsigned run = 0;
        for (int t = 0; t < 256; ++t) { unsigned tmp = csum[t]; csum[t] = run; run += tmp; }
    }
    __syncthreads();
    unsigned before = csum[tid];
    if (before < TOPK && before + s >= TOPK) {
        unsigned cum = before;
#pragma unroll
        for (int j = 0; j < 16; ++j) {
            cum += binsum[j];
            if (cum >= TOPK) { s_t = hi - j; break; }
        }
    }
    __syncthreads();
    int t = s_t;

    // gather slice
    for (int i = bx * 256 + tid; i < NN / 4; i += NPART * 256) {
        float4 v = sc4[i];
        unsigned keys[4] = { __float_as_uint(v.x), __float_as_uint(v.y),
                             __float_as_uint(v.z), __float_as_uint(v.w) };
#pragma unroll
        for (int j = 0; j < 4; ++j) {
            if (bin_of(keys[j]) >= t) {
                int pos = atomicAdd(cntb, 1);
                if (pos < CAP) cand[(size_t)b * CAP + pos] = 4 * i + j;
            }
        }
    }
    __threadfence();                  // publish cand slice
    __syncthreads();
    if (tid == 0)
        s_tick = __hip_atomic_fetch_add(done2, 1, __ATOMIC_ACQ_REL, __HIP_MEMORY_SCOPE_AGENT);
    __syncthreads();
    if (s_tick != NPART - 1) return;  // only last-arriving block runs P3
    __threadfence();                  // acquire side: see all cand slices

    // ---- P3: final select + NMS (proven R10 code, 256 threads) ----
    int M = __hip_atomic_load(cntb, __ATOMIC_ACQUIRE, __HIP_MEMORY_SCOPE_AGENT);
    if (M > CAP) M = CAP;

    for (int j = tid; j < M; j += 256) {
        int idx = cand[(size_t)b * CAP + j];
        k_idx[j] = idx;
        h[j] = __float_as_uint(sc[idx]);   // h reused as k_key
    }
    for (int i = tid; i < TOPK; i += 256) {
        out[b * TOPK + i] = 0;
        out[(BB + b) * TOPK + i] = 0;
    }
    for (int i = tid; i < 56; i += 256) { nms_x1[TOPK + i] = 0.f; nms_x2[TOPK + i] = 0.f; }
    __syncthreads();

    for (int j = tid; j < M; j += 256) {
        unsigned kj = h[j];
        int ij = k_idx[j];
        int rank = 0;
        for (int mm = 0; mm < M; ++mm) {
            unsigned km = h[mm];
            rank += (km > kj) || (km == kj && k_idx[mm] > ij);
        }
        if (rank < TOPK) { sel_k[rank] = kj; sel_i[rank] = ij; }
    }
    __syncthreads();

    if (tid < TOPK) {
        unsigned kj = sel_k[tid];
        int ij = sel_i[tid];
        int r2 = 0;
        for (int mm = 0; mm < TOPK; ++mm) {
            unsigned km = sel_k[mm];
            r2 += (km > kj) || (km == kj && sel_i[mm] < ij);
        }
        nms_i[r2] = ij;
        nms_x1[r2] = sg[2 * (size_t)ij];
        nms_x2[r2] = sg[2 * (size_t)ij + 1];
    }
    __syncthreads();

    if (tid >= 64) return;
    int lane = tid;
    float rx1[4], rx2[4];
#pragma unroll
    for (int k = 0; k < 4; ++k) {
        rx1[k] = nms_x1[k * 64 + lane];
        rx2[k] = nms_x2[k * 64 + lane];
    }
    unsigned long long m0 = ~0ull, m1 = ~0ull, m2 = ~0ull, m3 = 0xffull;

    int* keep = out + b * TOPK;
    for (int it = 0; it < TOPK; ++it) {
        int p;
        if (m0)      p = __ffsll(m0) - 1;
        else if (m1) p = 64 + __ffsll(m1) - 1;
        else if (m2) p = 128 + __ffsll(m2) - 1;
        else if (m3) p = 192 + __ffsll(m3) - 1;
        else break;

        float wx1 = nms_x1[p];
        float wx2 = nms_x2[p];
        if (lane == 0) keep[it] = nms_i[p];

        unsigned long long mw[4] = { m0, m1, m2, m3 };
        unsigned long long nm[4];
#pragma unroll
        for (int k = 0; k < 4; ++k) {
            bool alive = (mw[k] >> lane) & 1ull;
            bool kill = false;
            if (alive) {
                int pos = k * 64 + lane;
                if (pos == p) kill = true;
                else {
                    float inter = fminf(rx2[k], wx2) - fmaxf(rx1[k], wx1);
                    kill = inter > 0.f;
                }
            }
            nm[k] = __ballot(alive && !kill);
        }
        m0 = nm[0]; m1 = nm[1]; m2 = nm[2]; m3 = nm[3];
    }
}

extern "C" void kernel_launch(void* const* d_in, const int* in_sizes, int n_in,
                              void* d_out, int out_size, void* d_ws, size_t ws_size,
                              hipStream_t stream) {
    const float* logits = (const float*)d_in[0];   // (8, 200000, 81) f32
    const float* segs   = (const float*)d_in[1];   // (8, 200000, 2)  f32
    int* out = (int*)d_out;                        // (16, 200) int32

    char* ws = (char*)d_ws;
    float*    scores = (float*)ws;                                  // 6,400,000 B
    unsigned* parts  = (unsigned*)(ws + 6400000);                   // 2,097,152 B
    int*      syncw  = (int*)(ws + 6400000 + 2097152);              // 3*256*4 = 3072 B
    int*      cand   = (int*)(ws + 6400000 + 2097152 + 4096);       // 131,072 B

    dim3 sgrid(NN / 64, BB);                       // 3125 x 8
    scores_kernel<<<sgrid, 256, 0, stream>>>(logits, scores, syncw);
    dim3 tgrid(NPART, BB);                         // 128 co-resident blocks
    tail_fused<<<tgrid, 256, 0, stream>>>(scores, segs, parts, cand, syncw, out);
}

// Round 15
// 172.065 us; speedup vs baseline: 2.5208x; 1.1846x over previous
//
#include <hip/hip_runtime.h>
#include <hip/hip_bf16.h>
#include <math.h>

#define BB 8
#define NN 200000
#define CC 81
#define TOPK 200
#define CAP 4096
#define NBIN 4096
#define NPART 16
#define LCAP 512

static __device__ __forceinline__ int bin_of(unsigned key) {
    // score in [1/81, 1] -> exponent in [120,127]; bits above bit 25 constant.
    // 12-bit monotone bin: exp low-3 bits + top-9 mantissa bits.
    return (int)((key >> 14) & (NBIN - 1));
}

// ---------------------------------------------------------------------------
// Kernel A (v4, proven 89.6us @ ~92% achievable HBM, unchanged from R10).
// ---------------------------------------------------------------------------
__global__ __launch_bounds__(256) void scores_kernel(const float* __restrict__ logits,
                                                     float* __restrict__ scores) {
    __shared__ float ls[64 * CC];     // 5184 floats = 20.7 KB
    __shared__ float lsc[64];
    int tid = threadIdx.x;
    int b = blockIdx.y;
    size_t fbase = ((size_t)b * NN + (size_t)blockIdx.x * 64) * CC;  // 16B-aligned
    const float4* g4 = (const float4*)(logits + fbase);
    float4* l4 = (float4*)ls;

    int wbase = tid & ~63;            // wave-uniform base within block
#pragma unroll
    for (int k = 0; k < 5; ++k) {     // 5 full wave rounds = 1280 float4s
        __builtin_amdgcn_global_load_lds(
            (const __attribute__((address_space(1))) void*)(g4 + k * 256 + tid),
            (__attribute__((address_space(3))) void*)(l4 + k * 256 + wbase),
            16, 0, 0);
    }
    if (tid < 16) l4[1280 + tid] = g4[1280 + tid];   // tail 16 f4s, plain copy
    __syncthreads();                  // drains vmcnt incl. global_load_lds

    int r = tid >> 2;                 // row 0..63
    int q = tid & 3;                  // quarter
    const float* row = ls + r * CC;
    int head = (4 - (r & 3)) & 3;     // floats until 16B alignment (81r%4==r%4)
    int nf4 = (CC - head) >> 2;       // 19 or 20 aligned float4s
    int tail = CC - head - 4 * nf4;   // 0..3

    float m = -INFINITY, S = 0.0f;
    const float4* rp = (const float4*)(row + head);
    for (int j = q; j < nf4; j += 4) {
        float4 v = rp[j];
        m = fmaxf(fmaxf(fmaxf(m, v.x), v.y), fmaxf(v.z, v.w));
        S += __expf(v.x) + __expf(v.y) + __expf(v.z) + __expf(v.w);
    }
    if (q == 3) {
        for (int h2 = 0; h2 < head; ++h2) { float x = row[h2]; m = fmaxf(m, x); S += __expf(x); }
        for (int t2 = 0; t2 < tail; ++t2) { float x = row[CC - tail + t2]; m = fmaxf(m, x); S += __expf(x); }
    }
#pragma unroll
    for (int w = 1; w < 4; w <<= 1) {
        m = fmaxf(m, __shfl_xor(m, w, 64));
        S += __shfl_xor(S, w, 64);
    }
    if (q == 0) lsc[r] = __expf(m) / S;
    __syncthreads();
    if (tid < 64) scores[(size_t)b * NN + (size_t)blockIdx.x * 64 + tid] = lsc[tid];
}

// ---------------------------------------------------------------------------
// Kernel B (unchanged from R10): per-batch PARTIAL histograms, plain stores.
// grid (NPART, BB). Block (0,b) zeroes cnt[b].
// ---------------------------------------------------------------------------
__global__ __launch_bounds__(256) void hist_kernel(const float* __restrict__ scores,
                                                   unsigned* __restrict__ parts,
                                                   int* __restrict__ cnt) {
    __shared__ unsigned h[NBIN];
    int tid = threadIdx.x;
    int b = blockIdx.y;
    for (int i = tid; i < NBIN; i += 256) h[i] = 0u;
    if (blockIdx.x == 0 && tid == 0) cnt[b] = 0;
    __syncthreads();

    const float4* sc4 = (const float4*)(scores + (size_t)b * NN);
    for (int i = blockIdx.x * 256 + tid; i < NN / 4; i += NPART * 256) {
        float4 v = sc4[i];
        atomicAdd(&h[bin_of(__float_as_uint(v.x))], 1u);
        atomicAdd(&h[bin_of(__float_as_uint(v.y))], 1u);
        atomicAdd(&h[bin_of(__float_as_uint(v.z))], 1u);
        atomicAdd(&h[bin_of(__float_as_uint(v.w))], 1u);
    }
    __syncthreads();
    unsigned* gp = parts + ((size_t)b * NPART + blockIdx.x) * NBIN;
    for (int i = tid; i < NBIN; i += 256) gp[i] = h[i];
}

// ---------------------------------------------------------------------------
// Kernel C (v2): gather with TWO-PHASE compaction. The R10 version fired one
// device-scope atomicAdd on cnt[b] PER CANDIDATE (~450/batch) -- single-line
// RMW throughput ~25-40M/s makes that ~50-60us (mechanism calibrated by R13's
// +250us from ~10K appends). Now: LDS-atomic local buffer, ONE global
// atomicAdd per block (16/batch), bulk copy. Overflow path keeps correctness.
// grid (NPART, BB).
// ---------------------------------------------------------------------------
__global__ __launch_bounds__(256) void gather_kernel(const float* __restrict__ scores,
                                                     const unsigned* __restrict__ parts,
                                                     int* __restrict__ cand,
                                                     int* __restrict__ cnt) {
    __shared__ unsigned csum[256];
    __shared__ int s_t;
    __shared__ int lidx[LCAP];
    __shared__ int lcnt, lbase;
    int tid = threadIdx.x;
    int b = blockIdx.y;
    const unsigned* gp = parts + (size_t)b * NPART * NBIN;

    // exact rank-200 threshold from the NPART partial hists (proven R10 code)
    int hi = NBIN - 1 - 16 * tid;
    unsigned binsum[16];
    unsigned s = 0;
#pragma unroll
    for (int j = 0; j < 16; ++j) {
        unsigned acc = 0;
#pragma unroll
        for (int p = 0; p < NPART; ++p) acc += gp[p * NBIN + (hi - j)];
        binsum[j] = acc;
        s += acc;
    }
    csum[tid] = s;
    if (tid == 0) lcnt = 0;
    __syncthreads();
    if (tid == 0) {
        unsigned run = 0;
        for (int t = 0; t < 256; ++t) { unsigned tmp = csum[t]; csum[t] = run; run += tmp; }
    }
    __syncthreads();
    unsigned before = csum[tid];
    if (before < TOPK && before + s >= TOPK) {
        unsigned cum = before;
#pragma unroll
        for (int j = 0; j < 16; ++j) {
            cum += binsum[j];
            if (cum >= TOPK) { s_t = hi - j; break; }
        }
    }
    __syncthreads();
    int t = s_t;

    // phase 1: collect slice candidates into LDS (LDS atomics only)
    const float4* sc4 = (const float4*)(scores + (size_t)b * NN);
    for (int i = blockIdx.x * 256 + tid; i < NN / 4; i += NPART * 256) {
        float4 v = sc4[i];
        unsigned keys[4] = { __float_as_uint(v.x), __float_as_uint(v.y),
                             __float_as_uint(v.z), __float_as_uint(v.w) };
#pragma unroll
        for (int j = 0; j < 4; ++j) {
            if (bin_of(keys[j]) >= t) {
                int p = atomicAdd(&lcnt, 1);
                if (p < LCAP) lidx[p] = 4 * i + j;
                else {                       // overflow: rare, correct
                    int g = atomicAdd(&cnt[b], 1);
                    if (g < CAP) cand[(size_t)b * CAP + g] = 4 * i + j;
                }
            }
        }
    }
    __syncthreads();

    // phase 2: one global reservation per block, bulk copy
    int n = lcnt < LCAP ? lcnt : LCAP;
    if (tid == 0) lbase = atomicAdd(&cnt[b], n);
    __syncthreads();
    int base = lbase;
    for (int j = tid; j < n; j += 256) {
        int pos = base + j;
        if (pos < CAP) cand[(size_t)b * CAP + pos] = lidx[j];
    }
}

// ---------------------------------------------------------------------------
// Kernel D (unchanged from R10): final rank + mask-scan NMS. 1 block/batch.
// ---------------------------------------------------------------------------
__global__ __launch_bounds__(1024) void final_kernel(const float* __restrict__ scores,
                                                     const float* __restrict__ segs,
                                                     const int* __restrict__ cand,
                                                     const int* __restrict__ cnt,
                                                     int* __restrict__ out) {
    __shared__ unsigned k_key[CAP];
    __shared__ int k_idx[CAP];
    __shared__ unsigned sel_k[TOPK];
    __shared__ int sel_i[TOPK];
    __shared__ int nms_i[TOPK];
    __shared__ float nms_x1[TOPK + 56], nms_x2[TOPK + 56];  // padded: pos<256 reads safe

    int b = blockIdx.x;
    int tid = threadIdx.x;
    const float* sc = scores + (size_t)b * NN;
    const float* sg = segs + (size_t)b * NN * 2;
    int M = cnt[b]; if (M > CAP) M = CAP;

    for (int j = tid; j < M; j += 1024) {
        int idx = cand[(size_t)b * CAP + j];
        k_idx[j] = idx;
        k_key[j] = __float_as_uint(sc[idx]);
    }
    for (int i = tid; i < TOPK; i += 1024) {
        out[b * TOPK + i] = 0;
        out[(BB + b) * TOPK + i] = 0;
    }
    for (int i = tid; i < 56; i += 1024) { nms_x1[TOPK + i] = 0.f; nms_x2[TOPK + i] = 0.f; }
    __syncthreads();

    for (int j = tid; j < M; j += 1024) {
        unsigned kj = k_key[j];
        int ij = k_idx[j];
        int rank = 0;
        for (int m = 0; m < M; ++m) {
            unsigned km = k_key[m];
            rank += (km > kj) || (km == kj && k_idx[m] > ij);
        }
        if (rank < TOPK) { sel_k[rank] = kj; sel_i[rank] = ij; }
    }
    __syncthreads();

    if (tid < TOPK) {
        unsigned kj = sel_k[tid];
        int ij = sel_i[tid];
        int r2 = 0;
        for (int m = 0; m < TOPK; ++m) {
            unsigned km = sel_k[m];
            r2 += (km > kj) || (km == kj && sel_i[m] < ij);
        }
        nms_i[r2] = ij;
        nms_x1[r2] = sg[2 * (size_t)ij];
        nms_x2[r2] = sg[2 * (size_t)ij + 1];
    }
    __syncthreads();

    if (tid >= 64) return;
    int lane = tid;
    float rx1[4], rx2[4];
#pragma unroll
    for (int k = 0; k < 4; ++k) {
        rx1[k] = nms_x1[k * 64 + lane];
        rx2[k] = nms_x2[k * 64 + lane];
    }
    unsigned long long m0 = ~0ull, m1 = ~0ull, m2 = ~0ull, m3 = 0xffull;

    int* keep = out + b * TOPK;
    for (int it = 0; it < TOPK; ++it) {
        int p;
        if (m0)      p = __ffsll(m0) - 1;
        else if (m1) p = 64 + __ffsll(m1) - 1;
        else if (m2) p = 128 + __ffsll(m2) - 1;
        else if (m3) p = 192 + __ffsll(m3) - 1;
        else break;

        float wx1 = nms_x1[p];
        float wx2 = nms_x2[p];
        if (lane == 0) keep[it] = nms_i[p];

        unsigned long long mw[4] = { m0, m1, m2, m3 };
        unsigned long long nm[4];
#pragma unroll
        for (int k = 0; k < 4; ++k) {
            bool alive = (mw[k] >> lane) & 1ull;
            bool kill = false;
            if (alive) {
                int pos = k * 64 + lane;
                if (pos == p) kill = true;
                else {
                    float inter = fminf(rx2[k], wx2) - fmaxf(rx1[k], wx1);
                    kill = inter > 0.f;
                }
            }
            nm[k] = __ballot(alive && !kill);
        }
        m0 = nm[0]; m1 = nm[1]; m2 = nm[2]; m3 = nm[3];
    }
}

extern "C" void kernel_launch(void* const* d_in, const int* in_sizes, int n_in,
                              void* d_out, int out_size, void* d_ws, size_t ws_size,
                              hipStream_t stream) {
    const float* logits = (const float*)d_in[0];   // (8, 200000, 81) f32
    const float* segs   = (const float*)d_in[1];   // (8, 200000, 2)  f32
    int* out = (int*)d_out;                        // (16, 200) int32

    char* ws = (char*)d_ws;
    float*    scores = (float*)ws;                                  // 6,400,000 B
    unsigned* parts  = (unsigned*)(ws + 6400000);                   // 2,097,152 B
    int*      cnt    = (int*)(ws + 6400000 + 2097152);              // 32 B
    int*      cand   = (int*)(ws + 6400000 + 2097152 + 64);         // 131,072 B

    dim3 sgrid(NN / 64, BB);                       // 3125 x 8
    scores_kernel<<<sgrid, 256, 0, stream>>>(logits, scores);
    dim3 hgrid(NPART, BB);
    hist_kernel<<<hgrid, 256, 0, stream>>>(scores, parts, cnt);
    dim3 ggrid(NPART, BB);
    gather_kernel<<<ggrid, 256, 0, stream>>>(scores, parts, cand, cnt);
    final_kernel<<<BB, 1024, 0, stream>>>(scores, segs, cand, cnt, out);
}